// Round 3
// baseline (230.004 us; speedup 1.0000x reference)
//
#include <hip/hip_runtime.h>

typedef unsigned short u16;
typedef short bf16x8 __attribute__((ext_vector_type(8)));
typedef float f32x4 __attribute__((ext_vector_type(4)));

#define NROWS 16384
#define DIM 128

// exp(-2*sim) = exp2(sim * -2*log2(e)); scale folded into normalized B rows.
#define NEG2LOG2E -2.8853900817779268f

// round-to-nearest-even f32 -> bf16 (inputs are finite)
__device__ __forceinline__ u16 f2bf(float f) {
    unsigned int u = __float_as_uint(f);
    u += 0x7fffu + ((u >> 16) & 1u);
    return (u16)(u >> 16);
}

// One wave per row: L2-normalize rows of a and b, emit bf16.
// B rows additionally pre-scaled by -2*log2(e) so GEMM output feeds exp2 directly.
__global__ __launch_bounds__(256) void norm_kernel(
    const float* __restrict__ a, const float* __restrict__ b,
    u16* __restrict__ aO, u16* __restrict__ bO)
{
    int tid  = threadIdx.x;
    int lane = tid & 63;
    int w    = tid >> 6;
    long row = (long)blockIdx.x * 4 + w;

    const float2 va = ((const float2*)(a + row * DIM))[lane];
    float sa = va.x * va.x + va.y * va.y;
    #pragma unroll
    for (int off = 32; off; off >>= 1) sa += __shfl_xor(sa, off, 64);
    float inva = 1.0f / fmaxf(sqrtf(sa), 1e-12f);
    unsigned int pa = (unsigned int)f2bf(va.x * inva) | ((unsigned int)f2bf(va.y * inva) << 16);
    ((unsigned int*)(aO + row * DIM))[lane] = pa;

    const float2 vb = ((const float2*)(b + row * DIM))[lane];
    float sb = vb.x * vb.x + vb.y * vb.y;
    #pragma unroll
    for (int off = 32; off; off >>= 1) sb += __shfl_xor(sb, off, 64);
    float invb = NEG2LOG2E / fmaxf(sqrtf(sb), 1e-12f);
    unsigned int pb = (unsigned int)f2bf(vb.x * invb) | ((unsigned int)f2bf(vb.y * invb) << 16);
    ((unsigned int*)(bO + row * DIM))[lane] = pb;
}

// 128x128 C-tile per block; 4 waves in 2x2; 4x4 16x16x32 bf16 MFMA per wave.
// A tile staged to LDS (32 KB) via swizzled global_load_lds (iter-invariant
// pattern -> pointer increments). B fragments loaded directly global->VGPR
// (L2-served), issued before the barrier so they overlap the A DMA.
__global__ __launch_bounds__(256, 3) void gemm_kernel(
    const u16* __restrict__ A, const u16* __restrict__ B,
    const int* __restrict__ labels, float* __restrict__ partials)
{
    __shared__ u16 sA[128 * 128 / 2];   // 32 KB

    int tid  = threadIdx.x;
    int lane = tid & 63;
    int w    = tid >> 6;
    int wr   = w >> 1;
    int wc   = w & 1;
    int mrow = lane & 15;
    int q    = lane >> 4;

    int rowBase = blockIdx.y * 128;
    int colBase = blockIdx.x * 128;

    // --- A staging: swizzled chunks, pattern is iter-invariant ---
    {
        int m0  = tid >> 4;
        int kq0 = (tid & 15) ^ (m0 & 15);
        const u16* gp = A + (size_t)rowBase * DIM + (m0 * 16 + kq0) * 8;
        u16* lp = &sA[(size_t)tid * 8 - (size_t)lane * 8];   // wave-uniform base
        #pragma unroll
        for (int iter = 0; iter < 8; iter++) {
            __builtin_amdgcn_global_load_lds(
                (const __attribute__((address_space(1))) void*)gp,
                (__attribute__((address_space(3))) void*)lp, 16, 0, 0);
            gp += 2048;  // 16 rows * 256 B
            lp += 2048;
        }
    }

    // --- B fragments: direct global->VGPR, all 16, in flight with the DMA ---
    // frag(ks,ni): row n = colBase + wc*64 + ni*16 + mrow, k-chunk kq = ks*4+q
    const u16* gBf = B + (size_t)(colBase + wc * 64 + mrow) * DIM + q * 8;
    bf16x8 bF[4][4];
    #pragma unroll
    for (int ks = 0; ks < 4; ks++)
        #pragma unroll
        for (int ni = 0; ni < 4; ni++)
            bF[ks][ni] = *(const bf16x8*)(gBf + ni * (16 * DIM) + ks * 32);

    // A-fragment LDS byte offsets (ks=0); per-ks address = base ^ (ks<<6).
    int aOff[4];
    #pragma unroll
    for (int mi = 0; mi < 4; mi++) {
        int m = wr * 64 + mi * 16 + mrow;
        aOff[mi] = (m << 8) | ((q ^ (m & 15)) << 4);
    }

    f32x4 acc[4][4];
    #pragma unroll
    for (int mi = 0; mi < 4; mi++)
        #pragma unroll
        for (int ni = 0; ni < 4; ni++)
            acc[mi][ni] = (f32x4){0.f, 0.f, 0.f, 0.f};

    __syncthreads();

    const char* sAb = (const char*)sA;
    #pragma unroll
    for (int ks = 0; ks < 4; ks++) {
        bf16x8 aF[4];
        int x = ks << 6;
        #pragma unroll
        for (int mi = 0; mi < 4; mi++)
            aF[mi] = *(const bf16x8*)(sAb + (aOff[mi] ^ x));
        #pragma unroll
        for (int mi = 0; mi < 4; mi++)
            #pragma unroll
            for (int ni = 0; ni < 4; ni++)
                acc[mi][ni] = __builtin_amdgcn_mfma_f32_16x16x32_bf16(
                    aF[mi], bF[ks][ni], acc[mi][ni], 0, 0, 0);
    }

    // Labels loaded after MFMA (keeps MFMA-phase VGPR pressure low; L1/L2-hot).
    int iBase = rowBase + wr * 64 + q * 4;
    int jBase = colBase + wc * 64 + mrow;
    int li[16], lj[4];
    #pragma unroll
    for (int mi = 0; mi < 4; mi++)
        #pragma unroll
        for (int r = 0; r < 4; r++)
            li[mi * 4 + r] = labels[iBase + mi * 16 + r];
    #pragma unroll
    for (int ni = 0; ni < 4; ni++)
        lj[ni] = labels[jBase + ni * 16];

    // Epilogue: acc already = -2*log2e*sim; exp2 + label mask + local sum.
    float s0 = 0.0f, s1 = 0.0f;
    #pragma unroll
    for (int mi = 0; mi < 4; mi++)
        #pragma unroll
        for (int ni = 0; ni < 4; ni++)
            #pragma unroll
            for (int r = 0; r < 4; r++) {
                float e = __builtin_amdgcn_exp2f(acc[mi][ni][r]);
                float m = (li[mi * 4 + r] != lj[ni]) ? e : 0.0f;
                if (r & 1) s1 += m; else s0 += m;
            }
    float s = s0 + s1;

    #pragma unroll
    for (int off = 32; off; off >>= 1) s += __shfl_xor(s, off, 64);

    __syncthreads();                       // done with sA — reuse for reduction
    float* red = (float*)sA;
    if (lane == 0) red[w] = s;
    __syncthreads();
    if (tid == 0) {
        constexpr float SCALE = (float)(1.0 / (16384.0 * 16383.0));
        float t = (red[0] + red[1]) + (red[2] + red[3]);
        partials[blockIdx.y * 128 + blockIdx.x] = t * SCALE;
    }
}

__global__ __launch_bounds__(256) void reduce_kernel(
    const float* __restrict__ partials, float* __restrict__ out)
{
    int tid = threadIdx.x;
    const float4* p4 = (const float4*)partials;
    float s = 0.0f;
    #pragma unroll 4
    for (int i = tid; i < 4096; i += 256) {
        float4 v = p4[i];
        s += (v.x + v.y) + (v.z + v.w);
    }
    #pragma unroll
    for (int off = 32; off; off >>= 1) s += __shfl_xor(s, off, 64);
    __shared__ float red[4];
    if ((tid & 63) == 0) red[tid >> 6] = s;
    __syncthreads();
    if (tid == 0) out[0] = (red[0] + red[1]) + (red[2] + red[3]);
}

extern "C" void kernel_launch(void* const* d_in, const int* in_sizes, int n_in,
                              void* d_out, int out_size, void* d_ws, size_t ws_size,
                              hipStream_t stream) {
    const float* self_p = (const float*)d_in[0];
    const float* pos_p  = (const float*)d_in[1];
    const int*   labels = (const int*)d_in[2];
    float* out = (float*)d_out;

    u16* aB = (u16*)d_ws;                       // 4 MB bf16 normalized self
    u16* bB = aB + (size_t)NROWS * DIM;         // 4 MB bf16 normalized pos (pre-scaled)
    float* partials = (float*)(bB + (size_t)NROWS * DIM);  // 64 KB

    norm_kernel<<<NROWS / 4, 256, 0, stream>>>(self_p, pos_p, aB, bB);
    gemm_kernel<<<dim3(128, 128), 256, 0, stream>>>(aB, bB, labels, partials);
    reduce_kernel<<<1, 256, 0, stream>>>(partials, out);
}

// Round 4
// 135.425 us; speedup vs baseline: 1.6984x; 1.6984x over previous
//
#include <hip/hip_runtime.h>

typedef unsigned char u8;
typedef unsigned short u16;
typedef float f32x4 __attribute__((ext_vector_type(4)));

#define NROWS 16384
#define DIM 128

// exp(-2*sim) = exp2(sim * -2*log2(e)); scale folded into normalized B rows.
#define NEG2LOG2E -2.8853900817779268f

// One wave per row: L2-normalize rows of a and b, emit fp8 e4m3 (OCP).
// B rows pre-scaled by -2*log2(e) so GEMM output feeds exp2 directly.
__global__ __launch_bounds__(256) void norm_kernel(
    const float* __restrict__ a, const float* __restrict__ b,
    u8* __restrict__ aO, u8* __restrict__ bO)
{
    int tid  = threadIdx.x;
    int lane = tid & 63;
    int w    = tid >> 6;
    long row = (long)blockIdx.x * 4 + w;

    const float2 va = ((const float2*)(a + row * DIM))[lane];
    float sa = va.x * va.x + va.y * va.y;
    #pragma unroll
    for (int off = 32; off; off >>= 1) sa += __shfl_xor(sa, off, 64);
    float inva = 1.0f / fmaxf(sqrtf(sa), 1e-12f);
    unsigned int pa = (unsigned int)__builtin_amdgcn_cvt_pk_fp8_f32(
        va.x * inva, va.y * inva, 0, false);
    ((u16*)(aO + row * DIM))[lane] = (u16)(pa & 0xffffu);

    const float2 vb = ((const float2*)(b + row * DIM))[lane];
    float sb = vb.x * vb.x + vb.y * vb.y;
    #pragma unroll
    for (int off = 32; off; off >>= 1) sb += __shfl_xor(sb, off, 64);
    float invb = NEG2LOG2E / fmaxf(sqrtf(sb), 1e-12f);
    unsigned int pb = (unsigned int)__builtin_amdgcn_cvt_pk_fp8_f32(
        vb.x * invb, vb.y * invb, 0, false);
    ((u16*)(bO + row * DIM))[lane] = (u16)(pb & 0xffffu);
}

// 128x128 C-tile per block; 4 waves in 2x2; 4x4 16x16x32 fp8 MFMA per wave.
// A/B tiles are 16 KB fp8 slabs (row = 128 B), staged via global_load_lds
// width-16 with a 16-B-pair xor swizzle: LDS pair p of row m holds global
// pair p^(m&7). Fragment (8 B, k-chunk c = ks*4+q) sits at byte
//   m*128 + ((p ^ (m&7))<<4) + (q&1)*8,  p = ks*2 + (q>>1)
// -> per-ks address = base ^ (ks<<5): one v_xor per fragment.
__global__ __launch_bounds__(256, 3) void gemm_kernel(
    const u8* __restrict__ A, const u8* __restrict__ B,
    const int* __restrict__ labels, float* __restrict__ partials)
{
    __shared__ u8 sAB[32768];   // A tile @0, B tile @16384

    int tid  = threadIdx.x;
    int lane = tid & 63;
    int w    = tid >> 6;
    int wr   = w >> 1;
    int wc   = w & 1;
    int mrow = lane & 15;
    int q    = lane >> 4;

    int rowBase = blockIdx.y * 128;
    int colBase = blockIdx.x * 128;

    // --- staging: 2 x 16 KB, 4 iters x 256 threads x 16 B each, swizzled src ---
    {
        int m0 = tid >> 3;                  // row within 32-row group
        int p0 = tid & 7;                   // 16-B pair within row
        int srcOff = m0 * 128 + ((p0 ^ (m0 & 7)) << 4);
        const u8* gpA = A + (size_t)rowBase * DIM + srcOff;
        const u8* gpB = B + (size_t)colBase * DIM + srcOff;
        u8* lp = &sAB[(size_t)tid * 16 - (size_t)lane * 16];  // wave-uniform base
        #pragma unroll
        for (int iter = 0; iter < 4; iter++) {
            __builtin_amdgcn_global_load_lds(
                (const __attribute__((address_space(1))) void*)gpA,
                (__attribute__((address_space(3))) void*)lp, 16, 0, 0);
            __builtin_amdgcn_global_load_lds(
                (const __attribute__((address_space(1))) void*)gpB,
                (__attribute__((address_space(3))) void*)(lp + 16384), 16, 0, 0);
            gpA += 4096; gpB += 4096; lp += 4096;   // 32 rows * 128 B
        }
    }

    // Label preloads — overlap with the LDS DMA.
    int iBase = rowBase + wr * 64 + q * 4;
    int jBase = colBase + wc * 64 + mrow;
    int li[16], lj[4];
    #pragma unroll
    for (int mi = 0; mi < 4; mi++)
        #pragma unroll
        for (int r = 0; r < 4; r++)
            li[mi * 4 + r] = labels[iBase + mi * 16 + r];
    #pragma unroll
    for (int ni = 0; ni < 4; ni++)
        lj[ni] = labels[jBase + ni * 16];

    // Fragment LDS byte offsets (ks=0); per-ks address = base ^ (ks<<5).
    int aOff[4], bOff[4];
    int qh = (q >> 1), ql = (q & 1) << 3;
    #pragma unroll
    for (int mi = 0; mi < 4; mi++) {
        int m = wr * 64 + mi * 16 + mrow;
        aOff[mi] = m * 128 + ((qh ^ (m & 7)) << 4) + ql;
        int n = wc * 64 + mi * 16 + mrow;
        bOff[mi] = 16384 + n * 128 + ((qh ^ (n & 7)) << 4) + ql;
    }

    f32x4 acc[4][4];
    #pragma unroll
    for (int mi = 0; mi < 4; mi++)
        #pragma unroll
        for (int ni = 0; ni < 4; ni++)
            acc[mi][ni] = (f32x4){0.f, 0.f, 0.f, 0.f};

    __syncthreads();

    #pragma unroll
    for (int ks = 0; ks < 4; ks++) {
        long aF[4], bF[4];
        int x = ks << 5;
        #pragma unroll
        for (int mi = 0; mi < 4; mi++) {
            aF[mi] = *(const long*)(sAB + (aOff[mi] ^ x));
            bF[mi] = *(const long*)(sAB + (bOff[mi] ^ x));
        }
        #pragma unroll
        for (int mi = 0; mi < 4; mi++)
            #pragma unroll
            for (int ni = 0; ni < 4; ni++)
                acc[mi][ni] = __builtin_amdgcn_mfma_f32_16x16x32_fp8_fp8(
                    aF[mi], bF[ni], acc[mi][ni], 0, 0, 0);
    }

    // Epilogue: acc already = -2*log2e*sim; exp2 + label mask + local sum.
    float s0 = 0.0f, s1 = 0.0f;
    #pragma unroll
    for (int mi = 0; mi < 4; mi++)
        #pragma unroll
        for (int ni = 0; ni < 4; ni++)
            #pragma unroll
            for (int r = 0; r < 4; r++) {
                float e = __builtin_amdgcn_exp2f(acc[mi][ni][r]);
                float m = (li[mi * 4 + r] != lj[ni]) ? e : 0.0f;
                if (r & 1) s1 += m; else s0 += m;
            }
    float s = s0 + s1;

    #pragma unroll
    for (int off = 32; off; off >>= 1) s += __shfl_xor(s, off, 64);

    __syncthreads();                       // done with sAB — reuse for reduction
    float* red = (float*)sAB;
    if (lane == 0) red[w] = s;
    __syncthreads();
    if (tid == 0) {
        constexpr float SCALE = (float)(1.0 / (16384.0 * 16383.0));
        float t = (red[0] + red[1]) + (red[2] + red[3]);
        partials[blockIdx.y * 128 + blockIdx.x] = t * SCALE;
    }
}

__global__ __launch_bounds__(256) void reduce_kernel(
    const float* __restrict__ partials, float* __restrict__ out)
{
    int tid = threadIdx.x;
    const float4* p4 = (const float4*)partials;
    float s = 0.0f;
    #pragma unroll 4
    for (int i = tid; i < 4096; i += 256) {
        float4 v = p4[i];
        s += (v.x + v.y) + (v.z + v.w);
    }
    #pragma unroll
    for (int off = 32; off; off >>= 1) s += __shfl_xor(s, off, 64);
    __shared__ float red[4];
    if ((tid & 63) == 0) red[tid >> 6] = s;
    __syncthreads();
    if (tid == 0) out[0] = (red[0] + red[1]) + (red[2] + red[3]);
}

extern "C" void kernel_launch(void* const* d_in, const int* in_sizes, int n_in,
                              void* d_out, int out_size, void* d_ws, size_t ws_size,
                              hipStream_t stream) {
    const float* self_p = (const float*)d_in[0];
    const float* pos_p  = (const float*)d_in[1];
    const int*   labels = (const int*)d_in[2];
    float* out = (float*)d_out;

    u8* aB = (u8*)d_ws;                         // 2 MB fp8 normalized self
    u8* bB = aB + (size_t)NROWS * DIM;          // 2 MB fp8 normalized pos (pre-scaled)
    float* partials = (float*)(bB + (size_t)NROWS * DIM);  // 64 KB

    norm_kernel<<<NROWS / 4, 256, 0, stream>>>(self_p, pos_p, aB, bB);
    gemm_kernel<<<dim3(128, 128), 256, 0, stream>>>(aB, bB, labels, partials);
    reduce_kernel<<<1, 256, 0, stream>>>(partials, out);
}